// Round 6
// baseline (239.172 us; speedup 1.0000x reference)
//
#include <hip/hip_runtime.h>
#include <math.h>

#define N_NODES_C 100000
#define HALF_N    50000
#define DIM_C     128
#define M_SEL_C   4096
#define N_POS_C   32
#define N_NEG_C   256
#define QS4       (2.0f / 15.0f)   // |z_a - z_b| = QS4 * |q4_a - q4_b|

__device__ __forceinline__ float wsum64(float v) {
#pragma unroll
    for (int o = 32; o; o >>= 1) v += __shfl_xor(v, o, 64);
    return v;
}
__device__ __forceinline__ float hsum32(float v) {
#pragma unroll
    for (int o = 1; o < 32; o <<= 1) v += __shfl_xor(v, o, 64);
    return v;
}
// int sum within each 4-lane subgroup
__device__ __forceinline__ int gsum4(int v) {
    v += __shfl_xor(v, 1, 64);
    v += __shfl_xor(v, 2, 64);
    return v;
}

// v_sad_u8: per-byte |a-b| summed + acc (exact, int domain)
__device__ __forceinline__ unsigned sad8(unsigned a, unsigned b, unsigned acc) {
    unsigned d;
    asm volatile("v_sad_u8 %0, %1, %2, %3" : "=v"(d) : "v"(a), "v"(b), "v"(acc));
    return d;
}

// SAD of one 16-byte fragment (32 nibble-packed dims) vs pre-split center
__device__ __forceinline__ int sadrow4(uint4 b, const unsigned* cl, const unsigned* ch) {
    const unsigned M = 0x0F0F0F0Fu;
    unsigned s = 0;
    s = sad8(b.x & M, cl[0], s); s = sad8((b.x >> 4) & M, ch[0], s);
    s = sad8(b.y & M, cl[1], s); s = sad8((b.y >> 4) & M, ch[1], s);
    s = sad8(b.z & M, cl[2], s); s = sad8((b.z >> 4) & M, ch[2], s);
    s = sad8(b.w & M, cl[3], s); s = sad8((b.w >> 4) & M, ch[3], s);
    return (int)s;
}

// Fused: sigma = 1/(1+e^-x); Q4 table row = 64 B, byte b = dim 2b (lo) | dim 2b+1 (hi);
// L_deg = mean((Z@W_d - deg)^2) with z = 2*sigma-1 (full precision).
__global__ __launch_bounds__(256) void k_z_deg(
    const float* __restrict__ P, const float* __restrict__ Wd,
    const float* __restrict__ deg, unsigned short* __restrict__ Qh,
    float* __restrict__ out)
{
    const int lane = threadIdx.x & 63;
    const int sl   = lane & 31;
    const int hi   = lane >> 5;
    const int wv   = threadIdx.x >> 6;
    const int gw   = blockIdx.x * 4 + wv;
    const int nw   = gridDim.x * 4;
    const float4 w = *(const float4*)(Wd + 4 * sl);
    float acc = 0.0f;
    for (int pr = gw; pr < N_NODES_C / 2; pr += nw) {
        const int row = 2 * pr + hi;
        float4 p = *(const float4*)(P + (size_t)row * DIM_C + 4 * sl);
        float r0 = __fdividef(15.0f, 1.0f + __expf(-p.x));
        float r1 = __fdividef(15.0f, 1.0f + __expf(-p.y));
        float r2 = __fdividef(15.0f, 1.0f + __expf(-p.z));
        float r3 = __fdividef(15.0f, 1.0f + __expf(-p.w));
        unsigned q = __float2uint_rn(r0) | (__float2uint_rn(r1) << 4) |
                     (__float2uint_rn(r2) << 8) | (__float2uint_rn(r3) << 12);
        Qh[(size_t)row * (DIM_C / 4) + sl] = (unsigned short)q;
        float z0 = fmaf(r0, QS4, -1.0f), z1 = fmaf(r1, QS4, -1.0f);
        float z2 = fmaf(r2, QS4, -1.0f), z3 = fmaf(r3, QS4, -1.0f);
        float d4 = fmaf(z0, w.x, fmaf(z1, w.y, fmaf(z2, w.z, z3 * w.w)));
        d4 = hsum32(d4);
        if (sl == 0) { float d = d4 - deg[row]; acc = fmaf(d, d, acc); }
    }
    __shared__ float part[4];
    float a = wsum64(acc);
    if (lane == 0) part[wv] = a;
    __syncthreads();
    if (threadIdx.x == 0)
        atomicAdd(out + 2, (part[0] + part[1] + part[2] + part[3]) * (1.0f / N_NODES_C));
}

// Fused contrast on the 4-bit table, wave-per-node, with PHASE-SPLIT gathers:
// each wave partitions its neighbor indices into [low half | high half] of the
// table so the XCD-wide working set per phase is 3.2 MB (< 4 MiB L2).
__global__ __launch_bounds__(256, 6) void k_contrast(
    const uint4* __restrict__ Q4,    // row = 4 uint4
    const int* __restrict__ nodes,
    const int* __restrict__ pos_a, const int* __restrict__ neg_a,
    const int* __restrict__ pos_b, const int* __restrict__ neg_b,
    float* __restrict__ out)
{
    const int tid  = threadIdx.x;
    const int wv   = tid >> 6;
    const int lane = tid & 63;
    const int l4   = lane & 3;    // lane within row (16 B each)
    const int g    = lane >> 2;   // subgroup = row slot 0..15

    const int id   = blockIdx.x * 4 + wv;       // 0..8191
    const int sel  = id >> 12;
    const int m    = id & (M_SEL_C - 1);
    const int* __restrict__ pos_idx = sel ? pos_b : pos_a;
    const int* __restrict__ neg_idx = sel ? neg_b : neg_a;

    __shared__ int sNeg[4][N_NEG_C];
    __shared__ int sPos[4][N_POS_C];

    ((int4*)sNeg[wv])[lane] = ((const int4*)(neg_idx + m * N_NEG_C))[lane];
    if (lane < N_POS_C / 4)
        ((int4*)sPos[wv])[lane] = ((const int4*)(pos_idx + m * N_POS_C))[lane];
    const int node = nodes[m];
    uint4 c = Q4[((unsigned)node << 2) + l4];
    const unsigned M = 0x0F0F0F0Fu;
    unsigned cl[4] = { c.x & M, c.y & M, c.z & M, c.w & M };
    unsigned ch[4] = { (c.x >> 4) & M, (c.y >> 4) & M, (c.z >> 4) & M, (c.w >> 4) & M };
    __syncthreads();

    // ---- in-place partition of sNeg[wv] into [low | high] (order-invariant) ----
    {
        const unsigned long long lm = (1ull << lane) - 1ull;
        int v0 = sNeg[wv][lane];
        int v1 = sNeg[wv][64 + lane];
        int v2 = sNeg[wv][128 + lane];
        int v3 = sNeg[wv][192 + lane];
        int lowBase = 0, highTop = N_NEG_C;
        int vals[4] = { v0, v1, v2, v3 };
        int dsts[4];
#pragma unroll
        for (int r = 0; r < 4; ++r) {
            bool b = vals[r] < HALF_N;
            unsigned long long mk = __ballot(b);
            int nL = __popcll(mk);
            int rkL = (int)__popcll(mk & lm);
            int rkH = (int)__popcll(~mk & lm);
            dsts[r] = b ? (lowBase + rkL) : (highTop - 1 - rkH);
            lowBase += nL;
            highTop -= (64 - nL);
        }
#pragma unroll
        for (int r = 0; r < 4; ++r) sNeg[wv][dsts[r]] = vals[r];
    }
    // ---- partition sPos[wv] (32 entries, lanes 0-31) ----
    {
        int v = (lane < N_POS_C) ? sPos[wv][lane] : 0;
        bool b = (lane < N_POS_C) && (v < HALF_N);
        unsigned long long mk = __ballot(b);
        int nL = __popcll(mk);
        if (lane < N_POS_C) {
            const unsigned long long lm = (1ull << lane) - 1ull;
            int rkL = (int)__popcll(mk & lm);
            int rkH = (int)__popcll(~mk & lm & 0xFFFFFFFFull);
            int dst = b ? rkL : (nL + rkH);
            sPos[wv][dst] = v;
        }
    }
    // wave-synchronous LDS writes; compiler inserts lgkmcnt before reads

    // ---- positives: 32 rows = 2 wave-loads (partitioned order) ----
    int pn0 = sPos[wv][g], pn1 = sPos[wv][16 + g];
    uint4 pb0 = Q4[((unsigned)pn0 << 2) + l4];
    uint4 pb1 = Q4[((unsigned)pn1 << 2) + l4];
    int psi = sadrow4(pb0, cl, ch) + sadrow4(pb1, cl, ch);

    // ---- negatives: 256 rows = 16 wave-loads, 2 rounds of 8, in partitioned
    //      (low-first) order; LSE is order-invariant ----
    float mx = -1e30f, sm = 0.0f;
#pragma unroll 1
    for (int r = 0; r < 2; ++r) {
        int nn[8];
#pragma unroll
        for (int u = 0; u < 8; ++u) nn[u] = sNeg[wv][r * 128 + u * 16 + g];
        uint4 nb[8];
#pragma unroll
        for (int u = 0; u < 8; ++u) nb[u] = Q4[((unsigned)nn[u] << 2) + l4];
#pragma unroll
        for (int u = 0; u < 8; ++u) {
            int s = gsum4(sadrow4(nb[u], cl, ch));
            float v = (float)s * QS4;
            float nm = fmaxf(mx, v);
            sm = fmaf(sm, __expf(mx - nm), __expf(v - nm));
            mx = nm;
        }
    }

    // ---- merge: LSE across 16 subgroup streams, pos across all 64 lanes ----
    float ps = (float)psi;
#pragma unroll
    for (int o = 1; o < 4; o <<= 1) ps += __shfl_xor(ps, o, 64);
#pragma unroll
    for (int o = 4; o < 64; o <<= 1) {
        float om = __shfl_xor(mx, o, 64);
        float os = __shfl_xor(sm, o, 64);
        float nm = fmaxf(mx, om);
        sm = fmaf(sm, __expf(mx - nm), os * __expf(om - nm));
        mx = nm;
        ps += __shfl_xor(ps, o, 64);
    }

    if (lane == 0) {
        float lse = mx + __logf(sm);
        float pm  = ps * QS4 * (1.0f / N_POS_C);
        atomicAdd(out + sel, lse - pm);
    }
}

extern "C" void kernel_launch(void* const* d_in, const int* in_sizes, int n_in,
                              void* d_out, int out_size, void* d_ws, size_t ws_size,
                              hipStream_t stream) {
    const float* P    = (const float*)d_in[0];
    const float* Wd   = (const float*)d_in[1];
    const float* deg  = (const float*)d_in[2];
    const int* nodes  = (const int*)d_in[3];
    const int* pos_i  = (const int*)d_in[4];
    const int* neg_i  = (const int*)d_in[5];
    const int* dpos_i = (const int*)d_in[6];
    const int* dneg_i = (const int*)d_in[7];
    float* out = (float*)d_out;
    unsigned short* Qh = (unsigned short*)d_ws;   // 100000*64 B = 6.4 MB

    hipMemsetAsync(out, 0, (size_t)out_size * sizeof(float), stream);
    k_z_deg<<<2048, 256, 0, stream>>>(P, Wd, deg, Qh, out);
    k_contrast<<<2048, 256, 0, stream>>>(
        (const uint4*)Qh, nodes, pos_i, neg_i, dpos_i, dneg_i, out);
}

// Round 7
// 237.816 us; speedup vs baseline: 1.0057x; 1.0057x over previous
//
#include <hip/hip_runtime.h>
#include <math.h>

#define N_NODES_C 100000
#define DIM_C     128
#define M_SEL_C   4096
#define N_POS_C   32
#define N_NEG_C   256
#define QS4       (2.0f / 15.0f)   // |z_a - z_b| = QS4 * |q4_a - q4_b|

__device__ __forceinline__ float wsum64(float v) {
#pragma unroll
    for (int o = 32; o; o >>= 1) v += __shfl_xor(v, o, 64);
    return v;
}
__device__ __forceinline__ float hsum32(float v) {
#pragma unroll
    for (int o = 1; o < 32; o <<= 1) v += __shfl_xor(v, o, 64);
    return v;
}
// int sum within each 4-lane subgroup
__device__ __forceinline__ int gsum4(int v) {
    v += __shfl_xor(v, 1, 64);
    v += __shfl_xor(v, 2, 64);
    return v;
}

// v_sad_u8: per-byte |a-b| summed + acc (exact, int domain)
__device__ __forceinline__ unsigned sad8(unsigned a, unsigned b, unsigned acc) {
    unsigned d;
    asm volatile("v_sad_u8 %0, %1, %2, %3" : "=v"(d) : "v"(a), "v"(b), "v"(acc));
    return d;
}

// SAD of one 16-byte fragment (32 nibble-packed dims) vs pre-split center
__device__ __forceinline__ int sadrow4(uint4 b, const unsigned* cl, const unsigned* ch) {
    const unsigned M = 0x0F0F0F0Fu;
    unsigned s = 0;
    s = sad8(b.x & M, cl[0], s); s = sad8((b.x >> 4) & M, ch[0], s);
    s = sad8(b.y & M, cl[1], s); s = sad8((b.y >> 4) & M, ch[1], s);
    s = sad8(b.z & M, cl[2], s); s = sad8((b.z >> 4) & M, ch[2], s);
    s = sad8(b.w & M, cl[3], s); s = sad8((b.w >> 4) & M, ch[3], s);
    return (int)s;
}

// Fused: sigma = 1/(1+e^-x); Q4 table row = 64 B, byte b = dim 2b (lo) | dim 2b+1 (hi);
// L_deg = mean((Z@W_d - deg)^2) with z = 2*sigma-1 (full precision).
__global__ __launch_bounds__(256) void k_z_deg(
    const float* __restrict__ P, const float* __restrict__ Wd,
    const float* __restrict__ deg, unsigned short* __restrict__ Qh,
    float* __restrict__ out)
{
    const int lane = threadIdx.x & 63;
    const int sl   = lane & 31;
    const int hi   = lane >> 5;
    const int wv   = threadIdx.x >> 6;
    const int gw   = blockIdx.x * 4 + wv;
    const int nw   = gridDim.x * 4;
    const float4 w = *(const float4*)(Wd + 4 * sl);
    float acc = 0.0f;
    for (int pr = gw; pr < N_NODES_C / 2; pr += nw) {
        const int row = 2 * pr + hi;
        float4 p = *(const float4*)(P + (size_t)row * DIM_C + 4 * sl);
        float r0 = __fdividef(15.0f, 1.0f + __expf(-p.x));
        float r1 = __fdividef(15.0f, 1.0f + __expf(-p.y));
        float r2 = __fdividef(15.0f, 1.0f + __expf(-p.z));
        float r3 = __fdividef(15.0f, 1.0f + __expf(-p.w));
        unsigned q = __float2uint_rn(r0) | (__float2uint_rn(r1) << 4) |
                     (__float2uint_rn(r2) << 8) | (__float2uint_rn(r3) << 12);
        Qh[(size_t)row * (DIM_C / 4) + sl] = (unsigned short)q;
        float z0 = fmaf(r0, QS4, -1.0f), z1 = fmaf(r1, QS4, -1.0f);
        float z2 = fmaf(r2, QS4, -1.0f), z3 = fmaf(r3, QS4, -1.0f);
        float d4 = fmaf(z0, w.x, fmaf(z1, w.y, fmaf(z2, w.z, z3 * w.w)));
        d4 = hsum32(d4);
        if (sl == 0) { float d = d4 - deg[row]; acc = fmaf(d, d, acc); }
    }
    __shared__ float part[4];
    float a = wsum64(acc);
    if (lane == 0) part[wv] = a;
    __syncthreads();
    if (threadIdx.x == 0)
        atomicAdd(out + 2, (part[0] + part[1] + part[2] + part[3]) * (1.0f / N_NODES_C));
}

// Fused contrast, 2 waves per (m,sel) pair: 4096 blocks x 4 waves = 16384 waves.
// Wave = one half (128 negs; half 1 also does the 32 pos). 4 lanes per 64-B row,
// 16 rows per wave-load, all indices preloaded, row prefetch depth 4,
// no main-loop barriers; one barrier to merge the pair halves via LDS.
__global__ __launch_bounds__(256, 8) void k_contrast(
    const uint4* __restrict__ Q4,    // row = 4 uint4
    const int* __restrict__ nodes,
    const int* __restrict__ pos_a, const int* __restrict__ neg_a,
    const int* __restrict__ pos_b, const int* __restrict__ neg_b,
    float* __restrict__ out)
{
    const int tid  = threadIdx.x;
    const int wv   = tid >> 6;
    const int lane = tid & 63;
    const int l4   = lane & 3;    // lane within row (16 B each)
    const int g    = lane >> 2;   // subgroup = row slot 0..15

    const int id   = blockIdx.x * 4 + wv;     // 0..16383
    const int pr   = id >> 1;                 // pair 0..8191
    const int half = id & 1;
    const int sel  = pr >> 12;
    const int m    = pr & (M_SEL_C - 1);
    const int* __restrict__ pos_idx = sel ? pos_b : pos_a;
    const int* __restrict__ neg_idx = sel ? neg_b : neg_a;

    const int node = nodes[m];
    uint4 c = Q4[((unsigned)node << 2) + l4];
    const unsigned M = 0x0F0F0F0Fu;
    unsigned cl[4] = { c.x & M, c.y & M, c.z & M, c.w & M };
    unsigned ch[4] = { (c.x >> 4) & M, (c.y >> 4) & M, (c.z >> 4) & M, (c.w >> 4) & M };

    // ---- preload all 8 neighbor indices for this half (coalesced 64-B reads) ----
    const int* __restrict__ np = neg_idx + m * N_NEG_C + half * 128;
    int nn[8];
#pragma unroll
    for (int t = 0; t < 8; ++t) nn[t] = np[t * 16 + g];

    // ---- negatives: 8 wave-loads of 16 rows, software pipeline depth 4 ----
    uint4 nb[4];
#pragma unroll
    for (int u = 0; u < 4; ++u) nb[u] = Q4[((unsigned)nn[u] << 2) + l4];

    float mx = -1e30f, sm = 0.0f;
#pragma unroll
    for (int t = 0; t < 8; ++t) {
        int s = gsum4(sadrow4(nb[t & 3], cl, ch));   // row total on all 4 lanes
        if (t < 4) nb[t & 3] = Q4[((unsigned)nn[t + 4] << 2) + l4];
        float v = (float)s * QS4;
        float nm = fmaxf(mx, v);
        sm = fmaf(sm, __expf(mx - nm), __expf(v - nm));
        mx = nm;
    }

    // ---- positives: only the half==1 wave, 32 rows = 2 wave-loads ----
    float ps = 0.0f;
    if (half) {
        const int* __restrict__ pq = pos_idx + m * N_POS_C;
        int p0 = pq[g], p1 = pq[16 + g];
        uint4 b0 = Q4[((unsigned)p0 << 2) + l4];
        uint4 b1 = Q4[((unsigned)p1 << 2) + l4];
        ps = (float)(sadrow4(b0, cl, ch) + sadrow4(b1, cl, ch));   // per-lane partial
    }

    // ---- in-wave merge: ps over lanes, LSE across 16 subgroup streams ----
#pragma unroll
    for (int o = 1; o < 4; o <<= 1) ps += __shfl_xor(ps, o, 64);
#pragma unroll
    for (int o = 4; o < 64; o <<= 1) {
        float om = __shfl_xor(mx, o, 64);
        float os = __shfl_xor(sm, o, 64);
        float nm = fmaxf(mx, om);
        sm = fmaf(sm, __expf(mx - nm), os * __expf(om - nm));
        mx = nm;
        ps += __shfl_xor(ps, o, 64);
    }

    // ---- cross-wave pair merge via LDS ----
    __shared__ float mrgM[4], mrgS[4], mrgP[4];
    if (lane == 0) { mrgM[wv] = mx; mrgS[wv] = sm; mrgP[wv] = ps; }
    __syncthreads();
    if (!(wv & 1) && lane == 0) {
        float m0 = mrgM[wv],     s0 = mrgS[wv];
        float m1 = mrgM[wv + 1], s1 = mrgS[wv + 1];
        float nm = fmaxf(m0, m1);
        float st = fmaf(s0, __expf(m0 - nm), s1 * __expf(m1 - nm));
        float lse = nm + __logf(st);
        float pm  = (mrgP[wv] + mrgP[wv + 1]) * QS4 * (1.0f / N_POS_C);
        atomicAdd(out + sel, lse - pm);
    }
}

extern "C" void kernel_launch(void* const* d_in, const int* in_sizes, int n_in,
                              void* d_out, int out_size, void* d_ws, size_t ws_size,
                              hipStream_t stream) {
    const float* P    = (const float*)d_in[0];
    const float* Wd   = (const float*)d_in[1];
    const float* deg  = (const float*)d_in[2];
    const int* nodes  = (const int*)d_in[3];
    const int* pos_i  = (const int*)d_in[4];
    const int* neg_i  = (const int*)d_in[5];
    const int* dpos_i = (const int*)d_in[6];
    const int* dneg_i = (const int*)d_in[7];
    float* out = (float*)d_out;
    unsigned short* Qh = (unsigned short*)d_ws;   // 100000*64 B = 6.4 MB

    hipMemsetAsync(out, 0, (size_t)out_size * sizeof(float), stream);
    k_z_deg<<<2048, 256, 0, stream>>>(P, Wd, deg, Qh, out);
    k_contrast<<<4096, 256, 0, stream>>>(
        (const uint4*)Qh, nodes, pos_i, neg_i, dpos_i, dneg_i, out);
}